// Round 4
// baseline (1061.082 us; speedup 1.0000x reference)
//
#include <hip/hip_runtime.h>

#define BATCH 8
#define CH    48
#define NPTS  4096
#define NBN   (BATCH*NPTS)
#define KNN   9
#define NQ    4                 // column quarters per row
#define QCOLS (NPTS/NQ)         // 1024
#define TCOLS 32                // columns per quarter-tile
#define NTILES (QCOLS/TCOLS)    // 32
#define RPB   64                // rows per block

typedef unsigned short u16;

// ---- KNN: block = 64 rows x 4 quarters. Mirrors reference arithmetic:
// xn = f / max(|f|,1e-12) (true division), sq = sum(xn^2),
// dist = (sq_n + sq_m) - 2*dot(xn_n, xn_m), all fp32. ----
__global__ __launch_bounds__(256)
void k_knn(const float* __restrict__ x, u16* __restrict__ nn) {
  __shared__ __align__(16) float tile[NQ * TCOLS * CH];   // 24576 B
  __shared__ float nrmS[NQ * TCOLS];
  __shared__ float csq[NQ * TCOLS];
  int tid = threadIdx.x;
  int r0 = blockIdx.x * RPB;
  int b  = r0 >> 12;
  int q  = tid >> 6;
  int lr = tid & 63;
  int n  = (r0 + lr) & (NPTS - 1);
  const float* xb = x + (size_t)b * CH * NPTS;

  // row fragment: lane-coalesced strided loads, then ref-style normalize
  float rf[CH];
#pragma unroll
  for (int c = 0; c < CH; ++c) rf[c] = xb[(size_t)c * NPTS + n];
  float sqn;
  {
    float a0 = 0, a1 = 0, a2 = 0, a3 = 0;
#pragma unroll
    for (int k = 0; k < CH; k += 4) {
      a0 += rf[k] * rf[k]; a1 += rf[k+1] * rf[k+1];
      a2 += rf[k+2] * rf[k+2]; a3 += rf[k+3] * rf[k+3];
    }
    float nrm = fmaxf(sqrtf((a0 + a1) + (a2 + a3)), 1e-12f);
#pragma unroll
    for (int c = 0; c < CH; ++c) rf[c] = rf[c] / nrm;   // true division (ref)
    a0 = a1 = a2 = a3 = 0;
#pragma unroll
    for (int k = 0; k < CH; k += 4) {
      a0 += rf[k] * rf[k]; a1 += rf[k+1] * rf[k+1];
      a2 += rf[k+2] * rf[k+2]; a3 += rf[k+3] * rf[k+3];
    }
    sqn = (a0 + a1) + (a2 + a3);
  }

  float d[KNN]; int id[KNN];
#pragma unroll
  for (int j = 0; j < KNN; ++j) { d[j] = 3.4e38f; id[j] = 0x7fffffff; }

  for (int t = 0; t < NTILES; ++t) {
    __syncthreads();
    // stage 4 quarter-tiles (32 cols x 48 ch fp32), coalesced over columns
#pragma unroll
    for (int qq = 0; qq < NQ; ++qq) {
      int colbase = qq * QCOLS + t * TCOLS;
      float* dst = tile + qq * TCOLS * CH;
#pragma unroll
      for (int it = 0; it < 6; ++it) {
        int i = it * 256 + tid;          // 0..1535
        int c = i >> 5, p = i & 31;
        dst[p * CH + c] = xb[(size_t)c * NPTS + colbase + p];
      }
    }
    __syncthreads();
    if (tid < NQ * TCOLS) {              // per-column raw norm
      const float* cp = tile + tid * CH;
      float a0 = 0, a1 = 0, a2 = 0, a3 = 0;
#pragma unroll
      for (int k = 0; k < CH; k += 4) {
        float4 v = *(const float4*)(cp + k);
        a0 += v.x * v.x; a1 += v.y * v.y; a2 += v.z * v.z; a3 += v.w * v.w;
      }
      nrmS[tid] = fmaxf(sqrtf((a0 + a1) + (a2 + a3)), 1e-12f);
    }
    __syncthreads();
    for (int i = tid; i < NQ * TCOLS * CH; i += 256)   // true-division normalize
      tile[i] = tile[i] / nrmS[i / CH];
    __syncthreads();
    if (tid < NQ * TCOLS) {              // sq of normalized column
      const float* cp = tile + tid * CH;
      float a0 = 0, a1 = 0, a2 = 0, a3 = 0;
#pragma unroll
      for (int k = 0; k < CH; k += 4) {
        float4 v = *(const float4*)(cp + k);
        a0 += v.x * v.x; a1 += v.y * v.y; a2 += v.z * v.z; a3 += v.w * v.w;
      }
      csq[tid] = (a0 + a1) + (a2 + a3);
    }
    __syncthreads();

    int cbase = q * QCOLS + t * TCOLS;
    const float* tq = tile + q * TCOLS * CH;
    for (int cc = 0; cc < TCOLS; ++cc) {
      const float* cp = tq + cc * CH;    // all lanes same addr -> LDS broadcast
      float a0 = 0, a1 = 0, a2 = 0, a3 = 0;
#pragma unroll
      for (int k = 0; k < CH; k += 4) {
        float4 v = *(const float4*)(cp + k);
        a0 += rf[k] * v.x; a1 += rf[k+1] * v.y;
        a2 += rf[k+2] * v.z; a3 += rf[k+3] * v.w;
      }
      float dist = (sqn + csq[q * TCOLS + cc]) - 2.0f * ((a0 + a1) + (a2 + a3));
      if (dist < d[KNN - 1]) {           // cc ascends: strict < keeps lower idx on ties
        d[KNN - 1] = dist; id[KNN - 1] = cbase + cc;
#pragma unroll
        for (int k2 = KNN - 1; k2 > 0; --k2) {
          if (d[k2] < d[k2 - 1]) {
            float td = d[k2]; d[k2] = d[k2 - 1]; d[k2 - 1] = td;
            int ti = id[k2]; id[k2] = id[k2 - 1]; id[k2 - 1] = ti;
          }
        }
      }
    }
  }

  // merge 4 quarter lists per row (qq ascends = index-ascending: strict < stable)
  __syncthreads();
  float* md = tile;
  int*   mi = (int*)(tile + 256 * KNN);
#pragma unroll
  for (int j = 0; j < KNN; ++j) { md[tid * KNN + j] = d[j]; mi[tid * KNN + j] = id[j]; }
  __syncthreads();
  if (tid < RPB) {
    float fd[KNN]; int fi[KNN];
#pragma unroll
    for (int j = 0; j < KNN; ++j) { fd[j] = 3.4e38f; fi[j] = 0x7fffffff; }
    for (int qq = 0; qq < NQ; ++qq) {
      int s = qq * RPB + tid;
      for (int j = 0; j < KNN; ++j) {
        float dc = md[s * KNN + j]; int ic = mi[s * KNN + j];
        if (dc < fd[KNN - 1]) {
          fd[KNN - 1] = dc; fi[KNN - 1] = ic;
#pragma unroll
          for (int k2 = KNN - 1; k2 > 0; --k2) {
            if (fd[k2] < fd[k2 - 1]) {
              float td = fd[k2]; fd[k2] = fd[k2 - 1]; fd[k2 - 1] = td;
              int ti = fi[k2]; fi[k2] = fi[k2 - 1]; fi[k2 - 1] = ti;
            }
          }
        }
      }
    }
    u16* o = nn + (size_t)(r0 + tid) * KNN;
#pragma unroll
    for (int j = 0; j < KNN; ++j) o[j] = (u16)(fi[j] & (NPTS - 1));
  }
}

__global__ __launch_bounds__(256)
void k_zero(int* __restrict__ deg) { deg[blockIdx.x * 256 + threadIdx.x] = 0; }

__global__ __launch_bounds__(256)
void k_hist(const u16* __restrict__ nn, int* __restrict__ deg) {
  int node = blockIdx.x * 256 + threadIdx.x;
  int b12 = node & ~(NPTS - 1);
  int jmax = (node == NBN - 1) ? (KNN - 1) : KNN;   // linspace tail-edge drop
  for (int j = 0; j < jmax; ++j)
    atomicAdd(&deg[b12 + (nn[(size_t)node * KNN + j] & (NPTS - 1))], 1);
}

__global__ __launch_bounds__(256)
void k_dinv(const int* __restrict__ deg, float* __restrict__ dinv) {
  int i = blockIdx.x * 256 + threadIdx.x;
  int dg = deg[i];
  dinv[i] = (dg > 0) ? (1.0f / sqrtf((float)dg)) : 0.0f;
}

// ---- fused out = bias + f@W0 + Tx1@W1 (Tx1 gathered on the fly), fp32 ----
__global__ __launch_bounds__(256)
void k_out(const float* __restrict__ x, const u16* __restrict__ nn,
           const float* __restrict__ dinv,
           const float* __restrict__ W0, const float* __restrict__ W1,
           const float* __restrict__ bias, float* __restrict__ out) {
  __shared__ float w0[CH * CH], w1[CH * CH], bs[CH];
  for (int i = threadIdx.x; i < CH * CH; i += 256) { w0[i] = W0[i]; w1[i] = W1[i]; }
  if (threadIdx.x < CH) bs[threadIdx.x] = bias[threadIdx.x];
  __syncthreads();
  int node = blockIdx.x * 256 + threadIdx.x;
  int b = node >> 12, n = node & (NPTS - 1);
  const float* xb = x + (size_t)b * CH * NPTS;
  float f[CH], acc[CH], tx[CH];
#pragma unroll
  for (int c = 0; c < CH; ++c) f[c] = xb[(size_t)c * NPTS + n];
#pragma unroll
  for (int o = 0; o < CH; ++o) acc[o] = bs[o];
#pragma unroll
  for (int c = 0; c < CH; ++c) {
    float fc = f[c];
    const float* wr = w0 + c * CH;
#pragma unroll
    for (int o = 0; o < CH; ++o) acc[o] += fc * wr[o];
  }
#pragma unroll
  for (int c = 0; c < CH; ++c) tx[c] = 0.f;
  float dn = dinv[node];
  int jmax = (node == NBN - 1) ? (KNN - 1) : KNN;
  for (int j = 0; j < jmax; ++j) {
    int s = nn[(size_t)node * KNN + j] & (NPTS - 1);
    float w = -(dinv[(b << 12) + s] * dn);
#pragma unroll
    for (int c = 0; c < CH; ++c) tx[c] += w * xb[(size_t)c * NPTS + s];
  }
#pragma unroll
  for (int c = 0; c < CH; ++c) {
    float tc = tx[c];
    const float* wr = w1 + c * CH;
#pragma unroll
    for (int o = 0; o < CH; ++o) acc[o] += tc * wr[o];
  }
  float4* op = (float4*)(out + (size_t)node * CH);
#pragma unroll
  for (int i = 0; i < CH / 4; ++i)
    op[i] = make_float4(acc[4*i], acc[4*i+1], acc[4*i+2], acc[4*i+3]);
}

extern "C" void kernel_launch(void* const* d_in, const int* in_sizes, int n_in,
                              void* d_out, int out_size, void* d_ws, size_t ws_size,
                              hipStream_t stream) {
  const float* x    = (const float*)d_in[0];
  const float* W0   = (const float*)d_in[1];
  const float* W1   = (const float*)d_in[2];
  const float* bias = (const float*)d_in[3];
  float* out = (float*)d_out;
  char* w = (char*)d_ws;

  // workspace: 851,968 bytes total
  u16*   nn   = (u16*)w;                       // 589,824 B
  int*   deg  = (int*)(w + 589824);            // 131,072 B
  float* dinv = (float*)(w + 589824 + 131072); // 131,072 B

  k_knn  <<<NBN / RPB, 256, 0, stream>>>(x, nn);
  k_zero <<<NBN / 256, 256, 0, stream>>>(deg);
  k_hist <<<NBN / 256, 256, 0, stream>>>(nn, deg);
  k_dinv <<<NBN / 256, 256, 0, stream>>>(deg, dinv);
  k_out  <<<NBN / 256, 256, 0, stream>>>(x, nn, dinv, W0, W1, bias, out);
}

// Round 5
// 845.226 us; speedup vs baseline: 1.2554x; 1.2554x over previous
//
#include <hip/hip_runtime.h>

#define BATCH 8
#define CH    48
#define NPTS  4096
#define NBN   (BATCH*NPTS)
#define KNN   9

typedef unsigned short u16;

// ======================= FAST PATH (ws >= 13.57 MB) =======================
// k_prep: per node, read 48 strided fp32 (lane-coalesced), normalize per the
// reference (true division), store raw row (xraw), normalized row (xn), and
// csq = sum(xn^2). Node-major rows of 48 floats.
__global__ __launch_bounds__(256)
void k_prep(const float* __restrict__ x, float* __restrict__ xraw,
            float* __restrict__ xn, float* __restrict__ csq) {
  int node = blockIdx.x * 256 + threadIdx.x;
  int b = node >> 12, n = node & (NPTS - 1);
  const float* xb = x + (size_t)b * CH * NPTS;
  float f[CH];
#pragma unroll
  for (int c = 0; c < CH; ++c) f[c] = xb[(size_t)c * NPTS + n];
  float a0 = 0, a1 = 0, a2 = 0, a3 = 0;
#pragma unroll
  for (int k = 0; k < CH; k += 4) {
    a0 += f[k] * f[k]; a1 += f[k+1] * f[k+1];
    a2 += f[k+2] * f[k+2]; a3 += f[k+3] * f[k+3];
  }
  float nrm = fmaxf(sqrtf((a0 + a1) + (a2 + a3)), 1e-12f);
  float xv[CH];
#pragma unroll
  for (int c = 0; c < CH; ++c) xv[c] = f[c] / nrm;     // true division (ref)
  a0 = a1 = a2 = a3 = 0;
#pragma unroll
  for (int k = 0; k < CH; k += 4) {
    a0 += xv[k] * xv[k]; a1 += xv[k+1] * xv[k+1];
    a2 += xv[k+2] * xv[k+2]; a3 += xv[k+3] * xv[k+3];
  }
  csq[node] = (a0 + a1) + (a2 + a3);
  float4* ro = (float4*)(xraw + (size_t)node * CH);
  float4* no = (float4*)(xn   + (size_t)node * CH);
#pragma unroll
  for (int i = 0; i < CH / 4; ++i) {
    ro[i] = make_float4(f[4*i], f[4*i+1], f[4*i+2], f[4*i+3]);
    no[i] = make_float4(xv[4*i], xv[4*i+1], xv[4*i+2], xv[4*i+3]);
  }
}

// k_knn_f: block = 32 rows x 8 column-chunks (512 cols each). Grid = 1024.
// Stage 16 cols/chunk/iteration (24.6 KB LDS), inner loop: LDS-broadcast
// column reads (2 distinct addrs per wave = free 2-way), 48 fp32 FMA/col.
#define PQ    8      // column chunks
#define QC    (NPTS/PQ)   // 512
#define TC    16     // cols per chunk per stage
#define NST   (QC/TC)     // 32
#define RPBF  32     // rows per block

__global__ __launch_bounds__(256)
void k_knn_f(const float* __restrict__ xn, const float* __restrict__ csq,
             u16* __restrict__ nn) {
  __shared__ __align__(16) float tile[PQ * TC * CH];  // 6144 f = 24576 B
  __shared__ float csqS[PQ * TC];
  int tid = threadIdx.x;
  int r0 = blockIdx.x * RPBF;
  int b4096 = r0 & ~(NPTS - 1);
  int q  = tid >> 5;            // chunk 0..7
  int rp = tid & 31;
  int row = r0 + rp;

  const float* xnb = xn + (size_t)b4096 * CH;

  // per-stage static staging offsets (6 float4 per thread)
  int soff[6];
#pragma unroll
  for (int it = 0; it < 6; ++it) {
    int i = it * 256 + tid;               // 0..1535 float4 slots
    int chunk = i / (TC * 12);            // 192 f4 per chunk
    int rem = i - chunk * (TC * 12);
    int col = rem / 12, f4 = rem - col * 12;
    soff[it] = (chunk * QC + col) * CH + f4 * 4;   // + t*TC*CH per stage
  }

  float rf[CH];
  {
    const float4* rp4 = (const float4*)(xn + (size_t)row * CH);
#pragma unroll
    for (int i = 0; i < CH / 4; ++i) {
      float4 v = rp4[i];
      rf[4*i] = v.x; rf[4*i+1] = v.y; rf[4*i+2] = v.z; rf[4*i+3] = v.w;
    }
  }
  float sqn = csq[row];

  float d[KNN]; int id[KNN];
#pragma unroll
  for (int j = 0; j < KNN; ++j) { d[j] = 3.4e38f; id[j] = 0x7fffffff; }

  for (int t = 0; t < NST; ++t) {
    __syncthreads();
#pragma unroll
    for (int it = 0; it < 6; ++it) {
      int i = it * 256 + tid;
      *(float4*)(tile + i * 4) = *(const float4*)(xnb + soff[it] + t * (TC * CH));
    }
    if (tid < PQ * TC) {
      int chunk = tid >> 4, col = tid & 15;
      csqS[tid] = csq[b4096 + chunk * QC + t * TC + col];
    }
    __syncthreads();

    int cbase = q * QC + t * TC;
    const float* tq = tile + q * TC * CH;
    for (int cc = 0; cc < TC; ++cc) {
      const float* cp = tq + cc * CH;
      float a0 = 0, a1 = 0, a2 = 0, a3 = 0;
#pragma unroll
      for (int k = 0; k < CH; k += 4) {
        float4 v = *(const float4*)(cp + k);
        a0 += rf[k] * v.x; a1 += rf[k+1] * v.y;
        a2 += rf[k+2] * v.z; a3 += rf[k+3] * v.w;
      }
      float dist = (sqn + csqS[q * TC + cc]) - 2.0f * ((a0 + a1) + (a2 + a3));
      if (dist < d[KNN - 1]) {      // cc ascends: strict < keeps lower idx on ties
        d[KNN - 1] = dist; id[KNN - 1] = cbase + cc;
#pragma unroll
        for (int k2 = KNN - 1; k2 > 0; --k2) {
          if (d[k2] < d[k2 - 1]) {
            float td = d[k2]; d[k2] = d[k2 - 1]; d[k2 - 1] = td;
            int ti = id[k2]; id[k2] = id[k2 - 1]; id[k2 - 1] = ti;
          }
        }
      }
    }
  }

  // merge 8 chunk lists per row (chunk index ascending: strict < is stable)
  __syncthreads();
  float* md = tile;
  int*   mi = (int*)(tile + 256 * KNN);
#pragma unroll
  for (int j = 0; j < KNN; ++j) { md[tid * KNN + j] = d[j]; mi[tid * KNN + j] = id[j]; }
  __syncthreads();
  if (tid < RPBF) {
    float fd[KNN]; int fi[KNN];
#pragma unroll
    for (int j = 0; j < KNN; ++j) { fd[j] = 3.4e38f; fi[j] = 0x7fffffff; }
    for (int qq = 0; qq < PQ; ++qq) {
      int s = qq * RPBF + tid;
      for (int j = 0; j < KNN; ++j) {
        float dc = md[s * KNN + j]; int ic = mi[s * KNN + j];
        if (dc < fd[KNN - 1]) {
          fd[KNN - 1] = dc; fi[KNN - 1] = ic;
#pragma unroll
          for (int k2 = KNN - 1; k2 > 0; --k2) {
            if (fd[k2] < fd[k2 - 1]) {
              float td = fd[k2]; fd[k2] = fd[k2 - 1]; fd[k2 - 1] = td;
              int ti = fi[k2]; fi[k2] = fi[k2 - 1]; fi[k2 - 1] = ti;
            }
          }
        }
      }
    }
    u16* o = nn + (size_t)(r0 + tid) * KNN;
#pragma unroll
    for (int j = 0; j < KNN; ++j) o[j] = (u16)(fi[j] & (NPTS - 1));
  }
}

// k_out_f: same arithmetic as the passing round-4 k_out, but gathers from
// node-major xraw (contiguous 192 B rows instead of 48 scattered lines).
__global__ __launch_bounds__(256)
void k_out_f(const float* __restrict__ xraw, const u16* __restrict__ nn,
             const float* __restrict__ dinv,
             const float* __restrict__ W0, const float* __restrict__ W1,
             const float* __restrict__ bias, float* __restrict__ out) {
  __shared__ float w0[CH * CH], w1[CH * CH], bs[CH];
  for (int i = threadIdx.x; i < CH * CH; i += 256) { w0[i] = W0[i]; w1[i] = W1[i]; }
  if (threadIdx.x < CH) bs[threadIdx.x] = bias[threadIdx.x];
  __syncthreads();
  int node = blockIdx.x * 256 + threadIdx.x;
  int b12 = node & ~(NPTS - 1);
  float f[CH], acc[CH], tx[CH];
  {
    const float4* p = (const float4*)(xraw + (size_t)node * CH);
#pragma unroll
    for (int i = 0; i < CH / 4; ++i) {
      float4 v = p[i];
      f[4*i] = v.x; f[4*i+1] = v.y; f[4*i+2] = v.z; f[4*i+3] = v.w;
    }
  }
#pragma unroll
  for (int o = 0; o < CH; ++o) acc[o] = bs[o];
#pragma unroll
  for (int c = 0; c < CH; ++c) {
    float fc = f[c];
    const float* wr = w0 + c * CH;
#pragma unroll
    for (int o = 0; o < CH; ++o) acc[o] += fc * wr[o];
  }
#pragma unroll
  for (int c = 0; c < CH; ++c) tx[c] = 0.f;
  float dn = dinv[node];
  int jmax = (node == NBN - 1) ? (KNN - 1) : KNN;
  for (int j = 0; j < jmax; ++j) {
    int s = nn[(size_t)node * KNN + j] & (NPTS - 1);
    float w = -(dinv[b12 + s] * dn);
    const float4* p = (const float4*)(xraw + (size_t)(b12 + s) * CH);
#pragma unroll
    for (int i = 0; i < CH / 4; ++i) {
      float4 v = p[i];
      tx[4*i]   += w * v.x; tx[4*i+1] += w * v.y;
      tx[4*i+2] += w * v.z; tx[4*i+3] += w * v.w;
    }
  }
#pragma unroll
  for (int c = 0; c < CH; ++c) {
    float tc = tx[c];
    const float* wr = w1 + c * CH;
#pragma unroll
    for (int o = 0; o < CH; ++o) acc[o] += tc * wr[o];
  }
  float4* op = (float4*)(out + (size_t)node * CH);
#pragma unroll
  for (int i = 0; i < CH / 4; ++i)
    op[i] = make_float4(acc[4*i], acc[4*i+1], acc[4*i+2], acc[4*i+3]);
}

// ======================= shared small kernels =======================
__global__ __launch_bounds__(256)
void k_zero(int* __restrict__ deg) { deg[blockIdx.x * 256 + threadIdx.x] = 0; }

__global__ __launch_bounds__(256)
void k_hist(const u16* __restrict__ nn, int* __restrict__ deg) {
  int node = blockIdx.x * 256 + threadIdx.x;
  int b12 = node & ~(NPTS - 1);
  int jmax = (node == NBN - 1) ? (KNN - 1) : KNN;   // linspace tail-edge drop
  for (int j = 0; j < jmax; ++j)
    atomicAdd(&deg[b12 + (nn[(size_t)node * KNN + j] & (NPTS - 1))], 1);
}

__global__ __launch_bounds__(256)
void k_dinv(const int* __restrict__ deg, float* __restrict__ dinv) {
  int i = blockIdx.x * 256 + threadIdx.x;
  int dg = deg[i];
  dinv[i] = (dg > 0) ? (1.0f / sqrtf((float)dg)) : 0.0f;
}

// ======================= FALLBACK (round-4, proven) =======================
#define NQ    4
#define QCOLS (NPTS/NQ)
#define TCOLS 32
#define NTILES (QCOLS/TCOLS)
#define RPB   64

__global__ __launch_bounds__(256)
void k_knn_nb(const float* __restrict__ x, u16* __restrict__ nn) {
  __shared__ __align__(16) float tile[NQ * TCOLS * CH];
  __shared__ float nrmS[NQ * TCOLS];
  __shared__ float csq[NQ * TCOLS];
  int tid = threadIdx.x;
  int r0 = blockIdx.x * RPB;
  int b  = r0 >> 12;
  int q  = tid >> 6;
  int lr = tid & 63;
  int n  = (r0 + lr) & (NPTS - 1);
  const float* xb = x + (size_t)b * CH * NPTS;
  float rf[CH];
#pragma unroll
  for (int c = 0; c < CH; ++c) rf[c] = xb[(size_t)c * NPTS + n];
  float sqn;
  {
    float a0 = 0, a1 = 0, a2 = 0, a3 = 0;
#pragma unroll
    for (int k = 0; k < CH; k += 4) {
      a0 += rf[k] * rf[k]; a1 += rf[k+1] * rf[k+1];
      a2 += rf[k+2] * rf[k+2]; a3 += rf[k+3] * rf[k+3];
    }
    float nrm = fmaxf(sqrtf((a0 + a1) + (a2 + a3)), 1e-12f);
#pragma unroll
    for (int c = 0; c < CH; ++c) rf[c] = rf[c] / nrm;
    a0 = a1 = a2 = a3 = 0;
#pragma unroll
    for (int k = 0; k < CH; k += 4) {
      a0 += rf[k] * rf[k]; a1 += rf[k+1] * rf[k+1];
      a2 += rf[k+2] * rf[k+2]; a3 += rf[k+3] * rf[k+3];
    }
    sqn = (a0 + a1) + (a2 + a3);
  }
  float d[KNN]; int id[KNN];
#pragma unroll
  for (int j = 0; j < KNN; ++j) { d[j] = 3.4e38f; id[j] = 0x7fffffff; }
  for (int t = 0; t < NTILES; ++t) {
    __syncthreads();
#pragma unroll
    for (int qq = 0; qq < NQ; ++qq) {
      int colbase = qq * QCOLS + t * TCOLS;
      float* dst = tile + qq * TCOLS * CH;
#pragma unroll
      for (int it = 0; it < 6; ++it) {
        int i = it * 256 + tid;
        int c = i >> 5, p = i & 31;
        dst[p * CH + c] = xb[(size_t)c * NPTS + colbase + p];
      }
    }
    __syncthreads();
    if (tid < NQ * TCOLS) {
      const float* cp = tile + tid * CH;
      float a0 = 0, a1 = 0, a2 = 0, a3 = 0;
#pragma unroll
      for (int k = 0; k < CH; k += 4) {
        float4 v = *(const float4*)(cp + k);
        a0 += v.x * v.x; a1 += v.y * v.y; a2 += v.z * v.z; a3 += v.w * v.w;
      }
      nrmS[tid] = fmaxf(sqrtf((a0 + a1) + (a2 + a3)), 1e-12f);
    }
    __syncthreads();
    for (int i = tid; i < NQ * TCOLS * CH; i += 256)
      tile[i] = tile[i] / nrmS[i / CH];
    __syncthreads();
    if (tid < NQ * TCOLS) {
      const float* cp = tile + tid * CH;
      float a0 = 0, a1 = 0, a2 = 0, a3 = 0;
#pragma unroll
      for (int k = 0; k < CH; k += 4) {
        float4 v = *(const float4*)(cp + k);
        a0 += v.x * v.x; a1 += v.y * v.y; a2 += v.z * v.z; a3 += v.w * v.w;
      }
      csq[tid] = (a0 + a1) + (a2 + a3);
    }
    __syncthreads();
    int cbase = q * QCOLS + t * TCOLS;
    const float* tq = tile + q * TCOLS * CH;
    for (int cc = 0; cc < TCOLS; ++cc) {
      const float* cp = tq + cc * CH;
      float a0 = 0, a1 = 0, a2 = 0, a3 = 0;
#pragma unroll
      for (int k = 0; k < CH; k += 4) {
        float4 v = *(const float4*)(cp + k);
        a0 += rf[k] * v.x; a1 += rf[k+1] * v.y;
        a2 += rf[k+2] * v.z; a3 += rf[k+3] * v.w;
      }
      float dist = (sqn + csq[q * TCOLS + cc]) - 2.0f * ((a0 + a1) + (a2 + a3));
      if (dist < d[KNN - 1]) {
        d[KNN - 1] = dist; id[KNN - 1] = cbase + cc;
#pragma unroll
        for (int k2 = KNN - 1; k2 > 0; --k2) {
          if (d[k2] < d[k2 - 1]) {
            float td = d[k2]; d[k2] = d[k2 - 1]; d[k2 - 1] = td;
            int ti = id[k2]; id[k2] = id[k2 - 1]; id[k2 - 1] = ti;
          }
        }
      }
    }
  }
  __syncthreads();
  float* md = tile;
  int*   mi = (int*)(tile + 256 * KNN);
#pragma unroll
  for (int j = 0; j < KNN; ++j) { md[tid * KNN + j] = d[j]; mi[tid * KNN + j] = id[j]; }
  __syncthreads();
  if (tid < RPB) {
    float fd[KNN]; int fi[KNN];
#pragma unroll
    for (int j = 0; j < KNN; ++j) { fd[j] = 3.4e38f; fi[j] = 0x7fffffff; }
    for (int qq = 0; qq < NQ; ++qq) {
      int s = qq * RPB + tid;
      for (int j = 0; j < KNN; ++j) {
        float dc = md[s * KNN + j]; int ic = mi[s * KNN + j];
        if (dc < fd[KNN - 1]) {
          fd[KNN - 1] = dc; fi[KNN - 1] = ic;
#pragma unroll
          for (int k2 = KNN - 1; k2 > 0; --k2) {
            if (fd[k2] < fd[k2 - 1]) {
              float td = fd[k2]; fd[k2] = fd[k2 - 1]; fd[k2 - 1] = td;
              int ti = fi[k2]; fi[k2] = fi[k2 - 1]; fi[k2 - 1] = ti;
            }
          }
        }
      }
    }
    u16* o = nn + (size_t)(r0 + tid) * KNN;
#pragma unroll
    for (int j = 0; j < KNN; ++j) o[j] = (u16)(fi[j] & (NPTS - 1));
  }
}

__global__ __launch_bounds__(256)
void k_out_nb(const float* __restrict__ x, const u16* __restrict__ nn,
              const float* __restrict__ dinv,
              const float* __restrict__ W0, const float* __restrict__ W1,
              const float* __restrict__ bias, float* __restrict__ out) {
  __shared__ float w0[CH * CH], w1[CH * CH], bs[CH];
  for (int i = threadIdx.x; i < CH * CH; i += 256) { w0[i] = W0[i]; w1[i] = W1[i]; }
  if (threadIdx.x < CH) bs[threadIdx.x] = bias[threadIdx.x];
  __syncthreads();
  int node = blockIdx.x * 256 + threadIdx.x;
  int b = node >> 12, n = node & (NPTS - 1);
  const float* xb = x + (size_t)b * CH * NPTS;
  float f[CH], acc[CH], tx[CH];
#pragma unroll
  for (int c = 0; c < CH; ++c) f[c] = xb[(size_t)c * NPTS + n];
#pragma unroll
  for (int o = 0; o < CH; ++o) acc[o] = bs[o];
#pragma unroll
  for (int c = 0; c < CH; ++c) {
    float fc = f[c];
    const float* wr = w0 + c * CH;
#pragma unroll
    for (int o = 0; o < CH; ++o) acc[o] += fc * wr[o];
  }
#pragma unroll
  for (int c = 0; c < CH; ++c) tx[c] = 0.f;
  float dn = dinv[node];
  int jmax = (node == NBN - 1) ? (KNN - 1) : KNN;
  for (int j = 0; j < jmax; ++j) {
    int s = nn[(size_t)node * KNN + j] & (NPTS - 1);
    float w = -(dinv[(b << 12) + s] * dn);
#pragma unroll
    for (int c = 0; c < CH; ++c) tx[c] += w * xb[(size_t)c * NPTS + s];
  }
#pragma unroll
  for (int c = 0; c < CH; ++c) {
    float tc = tx[c];
    const float* wr = w1 + c * CH;
#pragma unroll
    for (int o = 0; o < CH; ++o) acc[o] += tc * wr[o];
  }
  float4* op = (float4*)(out + (size_t)node * CH);
#pragma unroll
  for (int i = 0; i < CH / 4; ++i)
    op[i] = make_float4(acc[4*i], acc[4*i+1], acc[4*i+2], acc[4*i+3]);
}

extern "C" void kernel_launch(void* const* d_in, const int* in_sizes, int n_in,
                              void* d_out, int out_size, void* d_ws, size_t ws_size,
                              hipStream_t stream) {
  const float* x    = (const float*)d_in[0];
  const float* W0   = (const float*)d_in[1];
  const float* W1   = (const float*)d_in[2];
  const float* bias = (const float*)d_in[3];
  float* out = (float*)d_out;
  char* w = (char*)d_ws;

  const size_t SZ_XN   = (size_t)NBN * CH * 4;   // 6,291,456
  const size_t SZ_XRAW = (size_t)NBN * CH * 4;   // 6,291,456
  const size_t SZ_CSQ  = (size_t)NBN * 4;        //   131,072
  const size_t SZ_NN   = (size_t)NBN * KNN * 2;  //   589,824
  const size_t SZ_DEG  = (size_t)NBN * 4;        //   131,072
  const size_t needF = SZ_XN + SZ_XRAW + SZ_CSQ + SZ_NN + 2 * SZ_DEG; // 13,565,952

  if (ws_size >= needF) {          // FAST path
    float* xn   = (float*)w;
    float* xraw = (float*)(w + SZ_XN);
    float* csq  = (float*)(w + SZ_XN + SZ_XRAW);
    u16*   nn   = (u16*)  (w + SZ_XN + SZ_XRAW + SZ_CSQ);
    int*   deg  = (int*)  (w + SZ_XN + SZ_XRAW + SZ_CSQ + SZ_NN);
    float* dinv = (float*)(w + SZ_XN + SZ_XRAW + SZ_CSQ + SZ_NN + SZ_DEG);
    k_prep  <<<NBN / 256,  256, 0, stream>>>(x, xraw, xn, csq);
    k_knn_f <<<NBN / RPBF, 256, 0, stream>>>(xn, csq, nn);
    k_zero  <<<NBN / 256,  256, 0, stream>>>(deg);
    k_hist  <<<NBN / 256,  256, 0, stream>>>(nn, deg);
    k_dinv  <<<NBN / 256,  256, 0, stream>>>(deg, dinv);
    k_out_f <<<NBN / 256,  256, 0, stream>>>(xraw, nn, dinv, W0, W1, bias, out);
  } else {                         // FALLBACK: proven round-4 path (852 KB)
    u16*   nn   = (u16*)w;
    int*   deg  = (int*)(w + SZ_NN);
    float* dinv = (float*)(w + SZ_NN + SZ_DEG);
    k_knn_nb <<<NBN / RPB, 256, 0, stream>>>(x, nn);
    k_zero   <<<NBN / 256, 256, 0, stream>>>(deg);
    k_hist   <<<NBN / 256, 256, 0, stream>>>(nn, deg);
    k_dinv   <<<NBN / 256, 256, 0, stream>>>(deg, dinv);
    k_out_nb <<<NBN / 256, 256, 0, stream>>>(x, nn, dinv, W0, W1, bias, out);
  }
}

// Round 6
// 831.126 us; speedup vs baseline: 1.2767x; 1.0170x over previous
//
#include <hip/hip_runtime.h>

#define BATCH 8
#define CH    48
#define NPTS  4096
#define NBN   (BATCH*NPTS)
#define KNN   9

typedef unsigned short u16;

// ======================= FAST PATH (ws >= 13.57 MB) =======================
// k_prep: per node normalize per reference (true division); write raw row,
// normalized row, csq = sum(xn^2). Also zero deg (used by fused hist).
__global__ __launch_bounds__(256)
void k_prep(const float* __restrict__ x, float* __restrict__ xraw,
            float* __restrict__ xn, float* __restrict__ csq,
            int* __restrict__ deg) {
  int node = blockIdx.x * 256 + threadIdx.x;
  deg[node] = 0;
  int b = node >> 12, n = node & (NPTS - 1);
  const float* xb = x + (size_t)b * CH * NPTS;
  float f[CH];
#pragma unroll
  for (int c = 0; c < CH; ++c) f[c] = xb[(size_t)c * NPTS + n];
  float a0 = 0, a1 = 0, a2 = 0, a3 = 0;
#pragma unroll
  for (int k = 0; k < CH; k += 4) {
    a0 += f[k] * f[k]; a1 += f[k+1] * f[k+1];
    a2 += f[k+2] * f[k+2]; a3 += f[k+3] * f[k+3];
  }
  float nrm = fmaxf(sqrtf((a0 + a1) + (a2 + a3)), 1e-12f);
  float xv[CH];
#pragma unroll
  for (int c = 0; c < CH; ++c) xv[c] = f[c] / nrm;     // true division (ref)
  a0 = a1 = a2 = a3 = 0;
#pragma unroll
  for (int k = 0; k < CH; k += 4) {
    a0 += xv[k] * xv[k]; a1 += xv[k+1] * xv[k+1];
    a2 += xv[k+2] * xv[k+2]; a3 += xv[k+3] * xv[k+3];
  }
  csq[node] = (a0 + a1) + (a2 + a3);
  float4* ro = (float4*)(xraw + (size_t)node * CH);
  float4* no = (float4*)(xn   + (size_t)node * CH);
#pragma unroll
  for (int i = 0; i < CH / 4; ++i) {
    ro[i] = make_float4(f[4*i], f[4*i+1], f[4*i+2], f[4*i+3]);
    no[i] = make_float4(xv[4*i], xv[4*i+1], xv[4*i+2], xv[4*i+3]);
  }
}

// k_knn: block = 64 rows x 8 column-chunks (512 threads). Grid = 512.
// Register-prefetched staging (global loads for stage t+1 issued before
// computing stage t) removes the barrier-drain HBM stall. Fused degree
// histogram in the epilogue.
#define PQ    8              // column chunks
#define QC    (NPTS/PQ)      // 512
#define TC    16             // cols per chunk per stage
#define NST   (QC/TC)        // 32
#define RPBF  64             // rows per block
#define THR   (PQ*RPBF)      // 512 threads

__global__ __launch_bounds__(512)
void k_knn(const float* __restrict__ xn, const float* __restrict__ csq,
           u16* __restrict__ nn, int* __restrict__ deg) {
  __shared__ __align__(16) float tile[PQ * TC * CH];  // 6144 f = 24576 B
  __shared__ float csqS[PQ * TC];                     // 128 f
  int tid = threadIdx.x;
  int r0 = blockIdx.x * RPBF;
  int b4096 = r0 & ~(NPTS - 1);
  int q  = tid >> 6;            // chunk 0..7 (wave-uniform)
  int rp = tid & 63;
  int row = r0 + rp;
  const float* xnb = xn + (size_t)b4096 * CH;

  // staging offsets: 3 float4 per thread, layout [chunk][col][f4]
  int soff[3];
#pragma unroll
  for (int it = 0; it < 3; ++it) {
    int i = it * THR + tid;               // 0..1535
    int chunk = i / 192;
    int rem = i - chunk * 192;
    int col = rem / 12, f4 = rem - col * 12;
    soff[it] = (chunk * QC + col) * CH + f4 * 4;
  }
  int cidx = 0;
  if (tid < PQ * TC) cidx = b4096 + (tid >> 4) * QC + (tid & 15);

  float rf[CH];
  {
    const float4* rp4 = (const float4*)(xn + (size_t)row * CH);
#pragma unroll
    for (int i = 0; i < CH / 4; ++i) {
      float4 v = rp4[i];
      rf[4*i] = v.x; rf[4*i+1] = v.y; rf[4*i+2] = v.z; rf[4*i+3] = v.w;
    }
  }
  float sqn = csq[row];

  float d[KNN]; int id[KNN];
#pragma unroll
  for (int j = 0; j < KNN; ++j) { d[j] = 3.4e38f; id[j] = 0x7fffffff; }

  // prologue: stage t=0
  float4 r[3]; float cpre = 0.f;
#pragma unroll
  for (int it = 0; it < 3; ++it) r[it] = *(const float4*)(xnb + soff[it]);
  if (tid < PQ * TC) cpre = csq[cidx];
#pragma unroll
  for (int it = 0; it < 3; ++it) *(float4*)(tile + (it * THR + tid) * 4) = r[it];
  if (tid < PQ * TC) csqS[tid] = cpre;
  __syncthreads();

  for (int t = 0; t < NST; ++t) {
    if (t + 1 < NST) {                    // prefetch next stage into regs
#pragma unroll
      for (int it = 0; it < 3; ++it)
        r[it] = *(const float4*)(xnb + soff[it] + (t + 1) * (TC * CH));
      if (tid < PQ * TC) cpre = csq[cidx + (t + 1) * TC];
    }
    int cbase = q * QC + t * TC;
    const float* tq = tile + q * (TC * CH);
    for (int cc = 0; cc < TC; ++cc) {
      const float* cp = tq + cc * CH;     // all 64 lanes same addr -> broadcast
      float a0 = 0, a1 = 0, a2 = 0, a3 = 0;
#pragma unroll
      for (int k = 0; k < CH; k += 4) {
        float4 v = *(const float4*)(cp + k);
        a0 += rf[k] * v.x; a1 += rf[k+1] * v.y;
        a2 += rf[k+2] * v.z; a3 += rf[k+3] * v.w;
      }
      float dist = (sqn + csqS[q * TC + cc]) - 2.0f * ((a0 + a1) + (a2 + a3));
      if (dist < d[KNN - 1]) {            // cc ascends: strict < keeps lower idx
        d[KNN - 1] = dist; id[KNN - 1] = cbase + cc;
#pragma unroll
        for (int k2 = KNN - 1; k2 > 0; --k2) {
          if (d[k2] < d[k2 - 1]) {
            float td = d[k2]; d[k2] = d[k2 - 1]; d[k2 - 1] = td;
            int ti = id[k2]; id[k2] = id[k2 - 1]; id[k2 - 1] = ti;
          }
        }
      }
    }
    __syncthreads();                      // all readers done with tile
    if (t + 1 < NST) {
#pragma unroll
      for (int it = 0; it < 3; ++it) *(float4*)(tile + (it * THR + tid) * 4) = r[it];
      if (tid < PQ * TC) csqS[tid] = cpre;
    }
    __syncthreads();                      // writes visible
  }

  // merge 8 chunk lists per row in two passes (chunk order ascending ->
  // strict < preserves the global lowest-index-first tie-break).
  float* md = tile;                       // 2304 f
  int*   mi = (int*)(tile + 2304);        // 2304 i (total 4608 <= 6144)
  float fd[KNN]; int fi[KNN];
#pragma unroll
  for (int j = 0; j < KNN; ++j) { fd[j] = 3.4e38f; fi[j] = 0x7fffffff; }

  if (tid < 256) {                        // pass A: chunks 0..3
#pragma unroll
    for (int j = 0; j < KNN; ++j) { md[tid * KNN + j] = d[j]; mi[tid * KNN + j] = id[j]; }
  }
  __syncthreads();
  if (tid < RPBF) {
    for (int qq = 0; qq < 4; ++qq) {
      int s = qq * RPBF + tid;
      for (int j = 0; j < KNN; ++j) {
        float dc = md[s * KNN + j]; int ic = mi[s * KNN + j];
        if (dc < fd[KNN - 1]) {
          fd[KNN - 1] = dc; fi[KNN - 1] = ic;
#pragma unroll
          for (int k2 = KNN - 1; k2 > 0; --k2) {
            if (fd[k2] < fd[k2 - 1]) {
              float td = fd[k2]; fd[k2] = fd[k2 - 1]; fd[k2 - 1] = td;
              int ti = fi[k2]; fi[k2] = fi[k2 - 1]; fi[k2 - 1] = ti;
            }
          }
        }
      }
    }
  }
  __syncthreads();
  if (tid >= 256) {                       // pass B: chunks 4..7
#pragma unroll
    for (int j = 0; j < KNN; ++j) {
      md[(tid - 256) * KNN + j] = d[j]; mi[(tid - 256) * KNN + j] = id[j];
    }
  }
  __syncthreads();
  if (tid < RPBF) {
    for (int qq = 0; qq < 4; ++qq) {
      int s = qq * RPBF + tid;
      for (int j = 0; j < KNN; ++j) {
        float dc = md[s * KNN + j]; int ic = mi[s * KNN + j];
        if (dc < fd[KNN - 1]) {
          fd[KNN - 1] = dc; fi[KNN - 1] = ic;
#pragma unroll
          for (int k2 = KNN - 1; k2 > 0; --k2) {
            if (fd[k2] < fd[k2 - 1]) {
              float td = fd[k2]; fd[k2] = fd[k2 - 1]; fd[k2 - 1] = td;
              int ti = fi[k2]; fi[k2] = fi[k2 - 1]; fi[k2 - 1] = ti;
            }
          }
        }
      }
    }
    int node = r0 + tid;
    u16* o = nn + (size_t)node * KNN;
    int jmax = (node == NBN - 1) ? (KNN - 1) : KNN;   // linspace tail drop
#pragma unroll
    for (int j = 0; j < KNN; ++j) o[j] = (u16)(fi[j] & (NPTS - 1));
    for (int j = 0; j < jmax; ++j)
      atomicAdd(&deg[b4096 + (fi[j] & (NPTS - 1))], 1);
  }
}

// k_out: fused out = bias + f@W0 + Tx1@W1; dinv recomputed inline from deg
// (bit-identical formula to the former k_dinv).
__global__ __launch_bounds__(256)
void k_out_f(const float* __restrict__ xraw, const u16* __restrict__ nn,
             const int* __restrict__ deg,
             const float* __restrict__ W0, const float* __restrict__ W1,
             const float* __restrict__ bias, float* __restrict__ out) {
  __shared__ float w0[CH * CH], w1[CH * CH], bs[CH];
  for (int i = threadIdx.x; i < CH * CH; i += 256) { w0[i] = W0[i]; w1[i] = W1[i]; }
  if (threadIdx.x < CH) bs[threadIdx.x] = bias[threadIdx.x];
  __syncthreads();
  int node = blockIdx.x * 256 + threadIdx.x;
  int b12 = node & ~(NPTS - 1);
  float f[CH], acc[CH], tx[CH];
  {
    const float4* p = (const float4*)(xraw + (size_t)node * CH);
#pragma unroll
    for (int i = 0; i < CH / 4; ++i) {
      float4 v = p[i];
      f[4*i] = v.x; f[4*i+1] = v.y; f[4*i+2] = v.z; f[4*i+3] = v.w;
    }
  }
#pragma unroll
  for (int o = 0; o < CH; ++o) acc[o] = bs[o];
#pragma unroll
  for (int c = 0; c < CH; ++c) {
    float fc = f[c];
    const float* wr = w0 + c * CH;
#pragma unroll
    for (int o = 0; o < CH; ++o) acc[o] += fc * wr[o];
  }
#pragma unroll
  for (int c = 0; c < CH; ++c) tx[c] = 0.f;
  int dgn = deg[node];
  float dn = (dgn > 0) ? (1.0f / sqrtf((float)dgn)) : 0.0f;
  int jmax = (node == NBN - 1) ? (KNN - 1) : KNN;
  for (int j = 0; j < jmax; ++j) {
    int s = nn[(size_t)node * KNN + j] & (NPTS - 1);
    int dgs = deg[b12 + s];
    float ds = (dgs > 0) ? (1.0f / sqrtf((float)dgs)) : 0.0f;
    float w = -(ds * dn);
    const float4* p = (const float4*)(xraw + (size_t)(b12 + s) * CH);
#pragma unroll
    for (int i = 0; i < CH / 4; ++i) {
      float4 v = p[i];
      tx[4*i]   += w * v.x; tx[4*i+1] += w * v.y;
      tx[4*i+2] += w * v.z; tx[4*i+3] += w * v.w;
    }
  }
#pragma unroll
  for (int c = 0; c < CH; ++c) {
    float tc = tx[c];
    const float* wr = w1 + c * CH;
#pragma unroll
    for (int o = 0; o < CH; ++o) acc[o] += tc * wr[o];
  }
  float4* op = (float4*)(out + (size_t)node * CH);
#pragma unroll
  for (int i = 0; i < CH / 4; ++i)
    op[i] = make_float4(acc[4*i], acc[4*i+1], acc[4*i+2], acc[4*i+3]);
}

// ======================= FALLBACK (round-4, proven) =======================
__global__ __launch_bounds__(256)
void k_zero(int* __restrict__ deg) { deg[blockIdx.x * 256 + threadIdx.x] = 0; }

__global__ __launch_bounds__(256)
void k_hist(const u16* __restrict__ nn, int* __restrict__ deg) {
  int node = blockIdx.x * 256 + threadIdx.x;
  int b12 = node & ~(NPTS - 1);
  int jmax = (node == NBN - 1) ? (KNN - 1) : KNN;
  for (int j = 0; j < jmax; ++j)
    atomicAdd(&deg[b12 + (nn[(size_t)node * KNN + j] & (NPTS - 1))], 1);
}

__global__ __launch_bounds__(256)
void k_dinv(const int* __restrict__ deg, float* __restrict__ dinv) {
  int i = blockIdx.x * 256 + threadIdx.x;
  int dg = deg[i];
  dinv[i] = (dg > 0) ? (1.0f / sqrtf((float)dg)) : 0.0f;
}

#define NQ    4
#define QCOLS (NPTS/NQ)
#define TCOLS 32
#define NTILES (QCOLS/TCOLS)
#define RPB   64

__global__ __launch_bounds__(256)
void k_knn_nb(const float* __restrict__ x, u16* __restrict__ nn) {
  __shared__ __align__(16) float tile[NQ * TCOLS * CH];
  __shared__ float nrmS[NQ * TCOLS];
  __shared__ float csq[NQ * TCOLS];
  int tid = threadIdx.x;
  int r0 = blockIdx.x * RPB;
  int b  = r0 >> 12;
  int q  = tid >> 6;
  int lr = tid & 63;
  int n  = (r0 + lr) & (NPTS - 1);
  const float* xb = x + (size_t)b * CH * NPTS;
  float rf[CH];
#pragma unroll
  for (int c = 0; c < CH; ++c) rf[c] = xb[(size_t)c * NPTS + n];
  float sqn;
  {
    float a0 = 0, a1 = 0, a2 = 0, a3 = 0;
#pragma unroll
    for (int k = 0; k < CH; k += 4) {
      a0 += rf[k] * rf[k]; a1 += rf[k+1] * rf[k+1];
      a2 += rf[k+2] * rf[k+2]; a3 += rf[k+3] * rf[k+3];
    }
    float nrm = fmaxf(sqrtf((a0 + a1) + (a2 + a3)), 1e-12f);
#pragma unroll
    for (int c = 0; c < CH; ++c) rf[c] = rf[c] / nrm;
    a0 = a1 = a2 = a3 = 0;
#pragma unroll
    for (int k = 0; k < CH; k += 4) {
      a0 += rf[k] * rf[k]; a1 += rf[k+1] * rf[k+1];
      a2 += rf[k+2] * rf[k+2]; a3 += rf[k+3] * rf[k+3];
    }
    sqn = (a0 + a1) + (a2 + a3);
  }
  float d[KNN]; int id[KNN];
#pragma unroll
  for (int j = 0; j < KNN; ++j) { d[j] = 3.4e38f; id[j] = 0x7fffffff; }
  for (int t = 0; t < NTILES; ++t) {
    __syncthreads();
#pragma unroll
    for (int qq = 0; qq < NQ; ++qq) {
      int colbase = qq * QCOLS + t * TCOLS;
      float* dst = tile + qq * TCOLS * CH;
#pragma unroll
      for (int it = 0; it < 6; ++it) {
        int i = it * 256 + tid;
        int c = i >> 5, p = i & 31;
        dst[p * CH + c] = xb[(size_t)c * NPTS + colbase + p];
      }
    }
    __syncthreads();
    if (tid < NQ * TCOLS) {
      const float* cp = tile + tid * CH;
      float a0 = 0, a1 = 0, a2 = 0, a3 = 0;
#pragma unroll
      for (int k = 0; k < CH; k += 4) {
        float4 v = *(const float4*)(cp + k);
        a0 += v.x * v.x; a1 += v.y * v.y; a2 += v.z * v.z; a3 += v.w * v.w;
      }
      nrmS[tid] = fmaxf(sqrtf((a0 + a1) + (a2 + a3)), 1e-12f);
    }
    __syncthreads();
    for (int i = tid; i < NQ * TCOLS * CH; i += 256)
      tile[i] = tile[i] / nrmS[i / CH];
    __syncthreads();
    if (tid < NQ * TCOLS) {
      const float* cp = tile + tid * CH;
      float a0 = 0, a1 = 0, a2 = 0, a3 = 0;
#pragma unroll
      for (int k = 0; k < CH; k += 4) {
        float4 v = *(const float4*)(cp + k);
        a0 += v.x * v.x; a1 += v.y * v.y; a2 += v.z * v.z; a3 += v.w * v.w;
      }
      csq[tid] = (a0 + a1) + (a2 + a3);
    }
    __syncthreads();
    int cbase = q * QCOLS + t * TCOLS;
    const float* tq = tile + q * TCOLS * CH;
    for (int cc = 0; cc < TCOLS; ++cc) {
      const float* cp = tq + cc * CH;
      float a0 = 0, a1 = 0, a2 = 0, a3 = 0;
#pragma unroll
      for (int k = 0; k < CH; k += 4) {
        float4 v = *(const float4*)(cp + k);
        a0 += rf[k] * v.x; a1 += rf[k+1] * v.y;
        a2 += rf[k+2] * v.z; a3 += rf[k+3] * v.w;
      }
      float dist = (sqn + csq[q * TCOLS + cc]) - 2.0f * ((a0 + a1) + (a2 + a3));
      if (dist < d[KNN - 1]) {
        d[KNN - 1] = dist; id[KNN - 1] = cbase + cc;
#pragma unroll
        for (int k2 = KNN - 1; k2 > 0; --k2) {
          if (d[k2] < d[k2 - 1]) {
            float td = d[k2]; d[k2] = d[k2 - 1]; d[k2 - 1] = td;
            int ti = id[k2]; id[k2] = id[k2 - 1]; id[k2 - 1] = ti;
          }
        }
      }
    }
  }
  __syncthreads();
  float* md = tile;
  int*   mi = (int*)(tile + 256 * KNN);
#pragma unroll
  for (int j = 0; j < KNN; ++j) { md[tid * KNN + j] = d[j]; mi[tid * KNN + j] = id[j]; }
  __syncthreads();
  if (tid < RPB) {
    float fd[KNN]; int fi[KNN];
#pragma unroll
    for (int j = 0; j < KNN; ++j) { fd[j] = 3.4e38f; fi[j] = 0x7fffffff; }
    for (int qq = 0; qq < NQ; ++qq) {
      int s = qq * RPB + tid;
      for (int j = 0; j < KNN; ++j) {
        float dc = md[s * KNN + j]; int ic = mi[s * KNN + j];
        if (dc < fd[KNN - 1]) {
          fd[KNN - 1] = dc; fi[KNN - 1] = ic;
#pragma unroll
          for (int k2 = KNN - 1; k2 > 0; --k2) {
            if (fd[k2] < fd[k2 - 1]) {
              float td = fd[k2]; fd[k2] = fd[k2 - 1]; fd[k2 - 1] = td;
              int ti = fi[k2]; fi[k2] = fi[k2 - 1]; fi[k2 - 1] = ti;
            }
          }
        }
      }
    }
    u16* o = nn + (size_t)(r0 + tid) * KNN;
#pragma unroll
    for (int j = 0; j < KNN; ++j) o[j] = (u16)(fi[j] & (NPTS - 1));
  }
}

__global__ __launch_bounds__(256)
void k_out_nb(const float* __restrict__ x, const u16* __restrict__ nn,
              const float* __restrict__ dinv,
              const float* __restrict__ W0, const float* __restrict__ W1,
              const float* __restrict__ bias, float* __restrict__ out) {
  __shared__ float w0[CH * CH], w1[CH * CH], bs[CH];
  for (int i = threadIdx.x; i < CH * CH; i += 256) { w0[i] = W0[i]; w1[i] = W1[i]; }
  if (threadIdx.x < CH) bs[threadIdx.x] = bias[threadIdx.x];
  __syncthreads();
  int node = blockIdx.x * 256 + threadIdx.x;
  int b = node >> 12, n = node & (NPTS - 1);
  const float* xb = x + (size_t)b * CH * NPTS;
  float f[CH], acc[CH], tx[CH];
#pragma unroll
  for (int c = 0; c < CH; ++c) f[c] = xb[(size_t)c * NPTS + n];
#pragma unroll
  for (int o = 0; o < CH; ++o) acc[o] = bs[o];
#pragma unroll
  for (int c = 0; c < CH; ++c) {
    float fc = f[c];
    const float* wr = w0 + c * CH;
#pragma unroll
    for (int o = 0; o < CH; ++o) acc[o] += fc * wr[o];
  }
#pragma unroll
  for (int c = 0; c < CH; ++c) tx[c] = 0.f;
  float dn = dinv[node];
  int jmax = (node == NBN - 1) ? (KNN - 1) : KNN;
  for (int j = 0; j < jmax; ++j) {
    int s = nn[(size_t)node * KNN + j] & (NPTS - 1);
    float w = -(dinv[(b << 12) + s] * dn);
#pragma unroll
    for (int c = 0; c < CH; ++c) tx[c] += w * xb[(size_t)c * NPTS + s];
  }
#pragma unroll
  for (int c = 0; c < CH; ++c) {
    float tc = tx[c];
    const float* wr = w1 + c * CH;
#pragma unroll
    for (int o = 0; o < CH; ++o) acc[o] += tc * wr[o];
  }
  float4* op = (float4*)(out + (size_t)node * CH);
#pragma unroll
  for (int i = 0; i < CH / 4; ++i)
    op[i] = make_float4(acc[4*i], acc[4*i+1], acc[4*i+2], acc[4*i+3]);
}

extern "C" void kernel_launch(void* const* d_in, const int* in_sizes, int n_in,
                              void* d_out, int out_size, void* d_ws, size_t ws_size,
                              hipStream_t stream) {
  const float* x    = (const float*)d_in[0];
  const float* W0   = (const float*)d_in[1];
  const float* W1   = (const float*)d_in[2];
  const float* bias = (const float*)d_in[3];
  float* out = (float*)d_out;
  char* w = (char*)d_ws;

  const size_t SZ_XN   = (size_t)NBN * CH * 4;   // 6,291,456
  const size_t SZ_XRAW = (size_t)NBN * CH * 4;   // 6,291,456
  const size_t SZ_CSQ  = (size_t)NBN * 4;        //   131,072
  const size_t SZ_NN   = (size_t)NBN * KNN * 2;  //   589,824
  const size_t SZ_DEG  = (size_t)NBN * 4;        //   131,072
  const size_t needF = SZ_XN + SZ_XRAW + SZ_CSQ + SZ_NN + 2 * SZ_DEG; // 13,565,952

  if (ws_size >= needF) {          // FAST path: 3 kernels
    float* xn   = (float*)w;
    float* xraw = (float*)(w + SZ_XN);
    float* csq  = (float*)(w + SZ_XN + SZ_XRAW);
    u16*   nn   = (u16*)  (w + SZ_XN + SZ_XRAW + SZ_CSQ);
    int*   deg  = (int*)  (w + SZ_XN + SZ_XRAW + SZ_CSQ + SZ_NN);
    k_prep  <<<NBN / 256,  256, 0, stream>>>(x, xraw, xn, csq, deg);
    k_knn   <<<NBN / RPBF, THR, 0, stream>>>(xn, csq, nn, deg);
    k_out_f <<<NBN / 256,  256, 0, stream>>>(xraw, nn, deg, W0, W1, bias, out);
  } else {                         // FALLBACK: proven round-4 path (852 KB)
    u16*   nn   = (u16*)w;
    int*   deg  = (int*)(w + SZ_NN);
    float* dinv = (float*)(w + SZ_NN + SZ_DEG);
    k_knn_nb <<<NBN / RPB, 256, 0, stream>>>(x, nn);
    k_zero   <<<NBN / 256, 256, 0, stream>>>(deg);
    k_hist   <<<NBN / 256, 256, 0, stream>>>(nn, deg);
    k_dinv   <<<NBN / 256, 256, 0, stream>>>(deg, dinv);
    k_out_nb <<<NBN / 256, 256, 0, stream>>>(x, nn, dinv, W0, W1, bias, out);
  }
}

// Round 7
// 496.822 us; speedup vs baseline: 2.1357x; 1.6729x over previous
//
#include <hip/hip_runtime.h>

#define BATCH 8
#define CH    48
#define NPTS  4096
#define NBN   (BATCH*NPTS)
#define KNN   9

typedef unsigned short u16;

// ======================= FAST PATH (ws >= 13.57 MB) =======================
// k_prep: per node normalize per reference (true division); write raw row,
// normalized row, csq = sum(xn^2). Also zero deg.
__global__ __launch_bounds__(256)
void k_prep(const float* __restrict__ x, float* __restrict__ xraw,
            float* __restrict__ xn, float* __restrict__ csq,
            int* __restrict__ deg) {
  int node = blockIdx.x * 256 + threadIdx.x;
  deg[node] = 0;
  int b = node >> 12, n = node & (NPTS - 1);
  const float* xb = x + (size_t)b * CH * NPTS;
  float f[CH];
#pragma unroll
  for (int c = 0; c < CH; ++c) f[c] = xb[(size_t)c * NPTS + n];
  float a0 = 0, a1 = 0, a2 = 0, a3 = 0;
#pragma unroll
  for (int k = 0; k < CH; k += 4) {
    a0 += f[k] * f[k]; a1 += f[k+1] * f[k+1];
    a2 += f[k+2] * f[k+2]; a3 += f[k+3] * f[k+3];
  }
  float nrm = fmaxf(sqrtf((a0 + a1) + (a2 + a3)), 1e-12f);
  float xv[CH];
#pragma unroll
  for (int c = 0; c < CH; ++c) xv[c] = f[c] / nrm;     // true division (ref)
  a0 = a1 = a2 = a3 = 0;
#pragma unroll
  for (int k = 0; k < CH; k += 4) {
    a0 += xv[k] * xv[k]; a1 += xv[k+1] * xv[k+1];
    a2 += xv[k+2] * xv[k+2]; a3 += xv[k+3] * xv[k+3];
  }
  csq[node] = (a0 + a1) + (a2 + a3);
  float4* ro = (float4*)(xraw + (size_t)node * CH);
  float4* no = (float4*)(xn   + (size_t)node * CH);
#pragma unroll
  for (int i = 0; i < CH / 4; ++i) {
    ro[i] = make_float4(f[4*i], f[4*i+1], f[4*i+2], f[4*i+3]);
    no[i] = make_float4(xv[4*i], xv[4*i+1], xv[4*i+2], xv[4*i+3]);
  }
}

// k_knn: 256 threads = 8 chunks x 32 slots, 2 rows/thread (64 rows/block).
// Each ds_read_b128 feeds 8 FMAs (2 rows) -> LDS-pipe cost halved vs R=1.
#define PQ    8              // column chunks
#define QC    (NPTS/PQ)      // 512
#define TC    8              // cols per chunk per stage
#define NST   (QC/TC)        // 64
#define RWB   64             // rows per block

__global__ __launch_bounds__(256)
void k_knn(const float* __restrict__ xn, const float* __restrict__ csq,
           u16* __restrict__ nn, int* __restrict__ deg) {
  __shared__ __align__(16) float tile[4608];   // staging 3072f; merge 2304f+2304i
  __shared__ float csqS[PQ * TC];              // 64
  int tid = threadIdx.x;
  int r0 = blockIdx.x * RWB;
  int b4096 = r0 & ~(NPTS - 1);
  int q    = tid >> 5;          // chunk 0..7 (2 distinct per wave = free)
  int slot = tid & 31;
  int row0 = r0 + 2 * slot;     // this thread's two rows
  const float* xnb = xn + (size_t)b4096 * CH;

  // staging offsets: 3 float4/thread, layout [chunk][col][12 f4]
  int soff[3], dto[3];
#pragma unroll
  for (int it = 0; it < 3; ++it) {
    int i = it * 256 + tid;               // 0..767
    int chunk = i / 96;
    int rem = i - chunk * 96;
    int col = rem / 12, f4 = rem - col * 12;
    soff[it] = (chunk * QC + col) * CH + f4 * 4;
    dto[it]  = (chunk * TC + col) * CH + f4 * 4;
  }
  int cidx = 0;
  if (tid < PQ * TC) cidx = b4096 + (tid >> 3) * QC + (tid & 7);

  float rf0[CH], rf1[CH];
  {
    const float4* p0 = (const float4*)(xn + (size_t)row0 * CH);
    const float4* p1 = (const float4*)(xn + (size_t)(row0 + 1) * CH);
#pragma unroll
    for (int i = 0; i < CH / 4; ++i) {
      float4 v = p0[i];
      rf0[4*i] = v.x; rf0[4*i+1] = v.y; rf0[4*i+2] = v.z; rf0[4*i+3] = v.w;
      float4 u = p1[i];
      rf1[4*i] = u.x; rf1[4*i+1] = u.y; rf1[4*i+2] = u.z; rf1[4*i+3] = u.w;
    }
  }
  float sqn0 = csq[row0], sqn1 = csq[row0 + 1];

  float d0[KNN], d1[KNN]; int id0[KNN], id1[KNN];
#pragma unroll
  for (int j = 0; j < KNN; ++j) {
    d0[j] = 3.4e38f; id0[j] = 0x7fffffff;
    d1[j] = 3.4e38f; id1[j] = 0x7fffffff;
  }

  // prologue: stage t=0
  float4 r[3]; float cpre = 0.f;
#pragma unroll
  for (int it = 0; it < 3; ++it) r[it] = *(const float4*)(xnb + soff[it]);
  if (tid < PQ * TC) cpre = csq[cidx];
#pragma unroll
  for (int it = 0; it < 3; ++it) *(float4*)(tile + dto[it]) = r[it];
  if (tid < PQ * TC) csqS[tid] = cpre;
  __syncthreads();

  for (int t = 0; t < NST; ++t) {
    if (t + 1 < NST) {                    // prefetch next stage into regs
#pragma unroll
      for (int it = 0; it < 3; ++it)
        r[it] = *(const float4*)(xnb + soff[it] + (t + 1) * (TC * CH));
      if (tid < PQ * TC) cpre = csq[cidx + (t + 1) * TC];
    }
    int cbase = q * QC + t * TC;
    const float* tq = tile + q * (TC * CH);
#pragma unroll
    for (int cc = 0; cc < TC; ++cc) {
      const float* cp = tq + cc * CH;     // 2 addrs per wave -> free broadcast
      float a0 = 0, a1 = 0, a2 = 0, a3 = 0;
      float e0 = 0, e1 = 0, e2 = 0, e3 = 0;
#pragma unroll
      for (int k = 0; k < CH; k += 4) {
        float4 v = *(const float4*)(cp + k);
        a0 += rf0[k] * v.x; a1 += rf0[k+1] * v.y;
        a2 += rf0[k+2] * v.z; a3 += rf0[k+3] * v.w;
        e0 += rf1[k] * v.x; e1 += rf1[k+1] * v.y;
        e2 += rf1[k+2] * v.z; e3 += rf1[k+3] * v.w;
      }
      float cs = csqS[q * TC + cc];
      float dist0 = (sqn0 + cs) - 2.0f * ((a0 + a1) + (a2 + a3));
      float dist1 = (sqn1 + cs) - 2.0f * ((e0 + e1) + (e2 + e3));
      int cid = cbase + cc;
      if (dist0 < d0[KNN - 1]) {          // cc ascends: strict < keeps lower idx
        d0[KNN - 1] = dist0; id0[KNN - 1] = cid;
#pragma unroll
        for (int k2 = KNN - 1; k2 > 0; --k2) {
          if (d0[k2] < d0[k2 - 1]) {
            float td = d0[k2]; d0[k2] = d0[k2 - 1]; d0[k2 - 1] = td;
            int ti = id0[k2]; id0[k2] = id0[k2 - 1]; id0[k2 - 1] = ti;
          }
        }
      }
      if (dist1 < d1[KNN - 1]) {
        d1[KNN - 1] = dist1; id1[KNN - 1] = cid;
#pragma unroll
        for (int k2 = KNN - 1; k2 > 0; --k2) {
          if (d1[k2] < d1[k2 - 1]) {
            float td = d1[k2]; d1[k2] = d1[k2 - 1]; d1[k2 - 1] = td;
            int ti = id1[k2]; id1[k2] = id1[k2 - 1]; id1[k2 - 1] = ti;
          }
        }
      }
    }
    __syncthreads();                      // readers done with tile
    if (t + 1 < NST) {
#pragma unroll
      for (int it = 0; it < 3; ++it) *(float4*)(tile + dto[it]) = r[it];
      if (tid < PQ * TC) csqS[tid] = cpre;
    }
    __syncthreads();                      // writes visible
  }

  // merge: 2 passes of 4 chunks (ascending chunk order -> stable tie-break)
  float* md = tile;                       // 2304 f
  int*   mi = (int*)(tile + 2304);        // 2304 i
  float fd[KNN]; int fi[KNN];
#pragma unroll
  for (int j = 0; j < KNN; ++j) { fd[j] = 3.4e38f; fi[j] = 0x7fffffff; }

  if (tid < 128) {                        // pass A: chunks 0..3
#pragma unroll
    for (int j = 0; j < KNN; ++j) {
      md[((2*slot)     * 4 + q) * KNN + j] = d0[j];
      mi[((2*slot)     * 4 + q) * KNN + j] = id0[j];
      md[((2*slot + 1) * 4 + q) * KNN + j] = d1[j];
      mi[((2*slot + 1) * 4 + q) * KNN + j] = id1[j];
    }
  }
  __syncthreads();
  if (tid < RWB) {
    for (int ch = 0; ch < 4; ++ch) {
      int s = tid * 4 + ch;
      for (int j = 0; j < KNN; ++j) {
        float dc = md[s * KNN + j]; int ic = mi[s * KNN + j];
        if (dc < fd[KNN - 1]) {
          fd[KNN - 1] = dc; fi[KNN - 1] = ic;
#pragma unroll
          for (int k2 = KNN - 1; k2 > 0; --k2) {
            if (fd[k2] < fd[k2 - 1]) {
              float td = fd[k2]; fd[k2] = fd[k2 - 1]; fd[k2 - 1] = td;
              int ti = fi[k2]; fi[k2] = fi[k2 - 1]; fi[k2 - 1] = ti;
            }
          }
        }
      }
    }
  }
  __syncthreads();
  if (tid >= 128) {                       // pass B: chunks 4..7
#pragma unroll
    for (int j = 0; j < KNN; ++j) {
      md[((2*slot)     * 4 + (q - 4)) * KNN + j] = d0[j];
      mi[((2*slot)     * 4 + (q - 4)) * KNN + j] = id0[j];
      md[((2*slot + 1) * 4 + (q - 4)) * KNN + j] = d1[j];
      mi[((2*slot + 1) * 4 + (q - 4)) * KNN + j] = id1[j];
    }
  }
  __syncthreads();
  if (tid < RWB) {
    for (int ch = 0; ch < 4; ++ch) {
      int s = tid * 4 + ch;
      for (int j = 0; j < KNN; ++j) {
        float dc = md[s * KNN + j]; int ic = mi[s * KNN + j];
        if (dc < fd[KNN - 1]) {
          fd[KNN - 1] = dc; fi[KNN - 1] = ic;
#pragma unroll
          for (int k2 = KNN - 1; k2 > 0; --k2) {
            if (fd[k2] < fd[k2 - 1]) {
              float td = fd[k2]; fd[k2] = fd[k2 - 1]; fd[k2 - 1] = td;
              int ti = fi[k2]; fi[k2] = fi[k2 - 1]; fi[k2 - 1] = ti;
            }
          }
        }
      }
    }
    int node = r0 + tid;
    u16* o = nn + (size_t)node * KNN;
    int jmax = (node == NBN - 1) ? (KNN - 1) : KNN;   // linspace tail drop
#pragma unroll
    for (int j = 0; j < KNN; ++j) o[j] = (u16)(fi[j] & (NPTS - 1));
    for (int j = 0; j < jmax; ++j)
      atomicAdd(&deg[b4096 + (fi[j] & (NPTS - 1))], 1);
  }
}

// k_out: 64 nodes/block x 4 threads/node (12 out-channels each). No spills:
// acc[12]+tx[12] in regs; f/tx rows in LDS (stride 52: aligned, conflict-free).
#define ONB 64
#define LPAD 52
__global__ __launch_bounds__(256)
void k_out_f(const float* __restrict__ xraw, const u16* __restrict__ nn,
             const int* __restrict__ deg,
             const float* __restrict__ W0, const float* __restrict__ W1,
             const float* __restrict__ bias, float* __restrict__ out) {
  __shared__ float w0[CH * CH], w1[CH * CH], bs[CH];
  __shared__ __align__(16) float fS[ONB * LPAD];
  __shared__ __align__(16) float txS[ONB * LPAD];
  __shared__ float dinvS[ONB];
  int tid = threadIdx.x;
  int n0 = blockIdx.x * ONB;
  int b12 = n0 & ~(NPTS - 1);
  for (int i = tid; i < CH * CH; i += 256) { w0[i] = W0[i]; w1[i] = W1[i]; }
  if (tid < CH) bs[tid] = bias[tid];
  for (int i = tid; i < ONB * 12; i += 256) {        // 768 float4
    int ln = i / 12, f4 = i % 12;
    *(float4*)(fS + ln * LPAD + f4 * 4) =
        *(const float4*)(xraw + (size_t)(n0 + ln) * CH + f4 * 4);
  }
  if (tid < ONB) {
    int dg = deg[n0 + tid];
    dinvS[tid] = (dg > 0) ? (1.0f / sqrtf((float)dg)) : 0.0f;
  }
  __syncthreads();

  int ln = tid >> 2, p = tid & 3;
  int node = n0 + ln;
  float dn = dinvS[ln];
  const u16* nrow = nn + (size_t)node * KNN;
  bool full = (node != NBN - 1);
  float tx[12];
#pragma unroll
  for (int i = 0; i < 12; ++i) tx[i] = 0.f;
#pragma unroll
  for (int j = 0; j < KNN; ++j) {
    if (j < KNN - 1 || full) {
      int s = nrow[j] & (NPTS - 1);
      int dgs = deg[b12 + s];
      float ds = (dgs > 0) ? (1.0f / sqrtf((float)dgs)) : 0.0f;
      float w = -(ds * dn);
      const float4* pr = (const float4*)(xraw + (size_t)(b12 + s) * CH + p * 12);
#pragma unroll
      for (int q3 = 0; q3 < 3; ++q3) {
        float4 v = pr[q3];
        tx[q3*4]   += w * v.x; tx[q3*4+1] += w * v.y;
        tx[q3*4+2] += w * v.z; tx[q3*4+3] += w * v.w;
      }
    }
  }
#pragma unroll
  for (int q3 = 0; q3 < 3; ++q3)
    *(float4*)(txS + ln * LPAD + p * 12 + q3 * 4) =
        make_float4(tx[q3*4], tx[q3*4+1], tx[q3*4+2], tx[q3*4+3]);
  __syncthreads();

  float acc[12];
#pragma unroll
  for (int i = 0; i < 12; ++i) acc[i] = bs[p * 12 + i];
  const float* fr = fS + ln * LPAD;
  const float* tr = txS + ln * LPAD;
#pragma unroll
  for (int c = 0; c < CH; ++c) {          // W0 pass (c ascending, as proven)
    float fc = fr[c];
    const float* wr = w0 + c * CH + p * 12;
#pragma unroll
    for (int i = 0; i < 12; ++i) acc[i] += fc * wr[i];
  }
#pragma unroll
  for (int c = 0; c < CH; ++c) {          // W1 pass
    float tc = tr[c];
    const float* wr = w1 + c * CH + p * 12;
#pragma unroll
    for (int i = 0; i < 12; ++i) acc[i] += tc * wr[i];
  }
  float* op = out + (size_t)node * CH + p * 12;
#pragma unroll
  for (int q3 = 0; q3 < 3; ++q3)
    *(float4*)(op + q3 * 4) =
        make_float4(acc[q3*4], acc[q3*4+1], acc[q3*4+2], acc[q3*4+3]);
}

// ======================= FALLBACK (round-4, proven) =======================
__global__ __launch_bounds__(256)
void k_zero(int* __restrict__ deg) { deg[blockIdx.x * 256 + threadIdx.x] = 0; }

__global__ __launch_bounds__(256)
void k_hist(const u16* __restrict__ nn, int* __restrict__ deg) {
  int node = blockIdx.x * 256 + threadIdx.x;
  int b12 = node & ~(NPTS - 1);
  int jmax = (node == NBN - 1) ? (KNN - 1) : KNN;
  for (int j = 0; j < jmax; ++j)
    atomicAdd(&deg[b12 + (nn[(size_t)node * KNN + j] & (NPTS - 1))], 1);
}

__global__ __launch_bounds__(256)
void k_dinv(const int* __restrict__ deg, float* __restrict__ dinv) {
  int i = blockIdx.x * 256 + threadIdx.x;
  int dg = deg[i];
  dinv[i] = (dg > 0) ? (1.0f / sqrtf((float)dg)) : 0.0f;
}

#define NQ    4
#define QCOLS (NPTS/NQ)
#define TCOLS 32
#define NTILES (QCOLS/TCOLS)
#define RPB   64

__global__ __launch_bounds__(256)
void k_knn_nb(const float* __restrict__ x, u16* __restrict__ nn) {
  __shared__ __align__(16) float tile[NQ * TCOLS * CH];
  __shared__ float nrmS[NQ * TCOLS];
  __shared__ float csq[NQ * TCOLS];
  int tid = threadIdx.x;
  int r0 = blockIdx.x * RPB;
  int b  = r0 >> 12;
  int q  = tid >> 6;
  int lr = tid & 63;
  int n  = (r0 + lr) & (NPTS - 1);
  const float* xb = x + (size_t)b * CH * NPTS;
  float rf[CH];
#pragma unroll
  for (int c = 0; c < CH; ++c) rf[c] = xb[(size_t)c * NPTS + n];
  float sqn;
  {
    float a0 = 0, a1 = 0, a2 = 0, a3 = 0;
#pragma unroll
    for (int k = 0; k < CH; k += 4) {
      a0 += rf[k] * rf[k]; a1 += rf[k+1] * rf[k+1];
      a2 += rf[k+2] * rf[k+2]; a3 += rf[k+3] * rf[k+3];
    }
    float nrm = fmaxf(sqrtf((a0 + a1) + (a2 + a3)), 1e-12f);
#pragma unroll
    for (int c = 0; c < CH; ++c) rf[c] = rf[c] / nrm;
    a0 = a1 = a2 = a3 = 0;
#pragma unroll
    for (int k = 0; k < CH; k += 4) {
      a0 += rf[k] * rf[k]; a1 += rf[k+1] * rf[k+1];
      a2 += rf[k+2] * rf[k+2]; a3 += rf[k+3] * rf[k+3];
    }
    sqn = (a0 + a1) + (a2 + a3);
  }
  float d[KNN]; int id[KNN];
#pragma unroll
  for (int j = 0; j < KNN; ++j) { d[j] = 3.4e38f; id[j] = 0x7fffffff; }
  for (int t = 0; t < NTILES; ++t) {
    __syncthreads();
#pragma unroll
    for (int qq = 0; qq < NQ; ++qq) {
      int colbase = qq * QCOLS + t * TCOLS;
      float* dst = tile + qq * TCOLS * CH;
#pragma unroll
      for (int it = 0; it < 6; ++it) {
        int i = it * 256 + tid;
        int c = i >> 5, p = i & 31;
        dst[p * CH + c] = xb[(size_t)c * NPTS + colbase + p];
      }
    }
    __syncthreads();
    if (tid < NQ * TCOLS) {
      const float* cp = tile + tid * CH;
      float a0 = 0, a1 = 0, a2 = 0, a3 = 0;
#pragma unroll
      for (int k = 0; k < CH; k += 4) {
        float4 v = *(const float4*)(cp + k);
        a0 += v.x * v.x; a1 += v.y * v.y; a2 += v.z * v.z; a3 += v.w * v.w;
      }
      nrmS[tid] = fmaxf(sqrtf((a0 + a1) + (a2 + a3)), 1e-12f);
    }
    __syncthreads();
    for (int i = tid; i < NQ * TCOLS * CH; i += 256)
      tile[i] = tile[i] / nrmS[i / CH];
    __syncthreads();
    if (tid < NQ * TCOLS) {
      const float* cp = tile + tid * CH;
      float a0 = 0, a1 = 0, a2 = 0, a3 = 0;
#pragma unroll
      for (int k = 0; k < CH; k += 4) {
        float4 v = *(const float4*)(cp + k);
        a0 += v.x * v.x; a1 += v.y * v.y; a2 += v.z * v.z; a3 += v.w * v.w;
      }
      csq[tid] = (a0 + a1) + (a2 + a3);
    }
    __syncthreads();
    int cbase = q * QCOLS + t * TCOLS;
    const float* tq = tile + q * TCOLS * CH;
    for (int cc = 0; cc < TCOLS; ++cc) {
      const float* cp = tq + cc * CH;
      float a0 = 0, a1 = 0, a2 = 0, a3 = 0;
#pragma unroll
      for (int k = 0; k < CH; k += 4) {
        float4 v = *(const float4*)(cp + k);
        a0 += rf[k] * v.x; a1 += rf[k+1] * v.y;
        a2 += rf[k+2] * v.z; a3 += rf[k+3] * v.w;
      }
      float dist = (sqn + csq[q * TCOLS + cc]) - 2.0f * ((a0 + a1) + (a2 + a3));
      if (dist < d[KNN - 1]) {
        d[KNN - 1] = dist; id[KNN - 1] = cbase + cc;
#pragma unroll
        for (int k2 = KNN - 1; k2 > 0; --k2) {
          if (d[k2] < d[k2 - 1]) {
            float td = d[k2]; d[k2] = d[k2 - 1]; d[k2 - 1] = td;
            int ti = id[k2]; id[k2] = id[k2 - 1]; id[k2 - 1] = ti;
          }
        }
      }
    }
  }
  __syncthreads();
  float* md = tile;
  int*   mi = (int*)(tile + 256 * KNN);
#pragma unroll
  for (int j = 0; j < KNN; ++j) { md[tid * KNN + j] = d[j]; mi[tid * KNN + j] = id[j]; }
  __syncthreads();
  if (tid < RPB) {
    float fd[KNN]; int fi[KNN];
#pragma unroll
    for (int j = 0; j < KNN; ++j) { fd[j] = 3.4e38f; fi[j] = 0x7fffffff; }
    for (int qq = 0; qq < NQ; ++qq) {
      int s = qq * RPB + tid;
      for (int j = 0; j < KNN; ++j) {
        float dc = md[s * KNN + j]; int ic = mi[s * KNN + j];
        if (dc < fd[KNN - 1]) {
          fd[KNN - 1] = dc; fi[KNN - 1] = ic;
#pragma unroll
          for (int k2 = KNN - 1; k2 > 0; --k2) {
            if (fd[k2] < fd[k2 - 1]) {
              float td = fd[k2]; fd[k2] = fd[k2 - 1]; fd[k2 - 1] = td;
              int ti = fi[k2]; fi[k2] = fi[k2 - 1]; fi[k2 - 1] = ti;
            }
          }
        }
      }
    }
    u16* o = nn + (size_t)(r0 + tid) * KNN;
#pragma unroll
    for (int j = 0; j < KNN; ++j) o[j] = (u16)(fi[j] & (NPTS - 1));
  }
}

__global__ __launch_bounds__(256)
void k_out_nb(const float* __restrict__ x, const u16* __restrict__ nn,
              const float* __restrict__ dinv,
              const float* __restrict__ W0, const float* __restrict__ W1,
              const float* __restrict__ bias, float* __restrict__ out) {
  __shared__ float w0[CH * CH], w1[CH * CH], bs[CH];
  for (int i = threadIdx.x; i < CH * CH; i += 256) { w0[i] = W0[i]; w1[i] = W1[i]; }
  if (threadIdx.x < CH) bs[threadIdx.x] = bias[threadIdx.x];
  __syncthreads();
  int node = blockIdx.x * 256 + threadIdx.x;
  int b = node >> 12, n = node & (NPTS - 1);
  const float* xb = x + (size_t)b * CH * NPTS;
  float f[CH], acc[CH], tx[CH];
#pragma unroll
  for (int c = 0; c < CH; ++c) f[c] = xb[(size_t)c * NPTS + n];
#pragma unroll
  for (int o = 0; o < CH; ++o) acc[o] = bs[o];
#pragma unroll
  for (int c = 0; c < CH; ++c) {
    float fc = f[c];
    const float* wr = w0 + c * CH;
#pragma unroll
    for (int o = 0; o < CH; ++o) acc[o] += fc * wr[o];
  }
#pragma unroll
  for (int c = 0; c < CH; ++c) tx[c] = 0.f;
  float dn = dinv[node];
  int jmax = (node == NBN - 1) ? (KNN - 1) : KNN;
  for (int j = 0; j < jmax; ++j) {
    int s = nn[(size_t)node * KNN + j] & (NPTS - 1);
    float w = -(dinv[(b << 12) + s] * dn);
#pragma unroll
    for (int c = 0; c < CH; ++c) tx[c] += w * xb[(size_t)c * NPTS + s];
  }
#pragma unroll
  for (int c = 0; c < CH; ++c) {
    float tc = tx[c];
    const float* wr = w1 + c * CH;
#pragma unroll
    for (int o = 0; o < CH; ++o) acc[o] += tc * wr[o];
  }
  float4* op = (float4*)(out + (size_t)node * CH);
#pragma unroll
  for (int i = 0; i < CH / 4; ++i)
    op[i] = make_float4(acc[4*i], acc[4*i+1], acc[4*i+2], acc[4*i+3]);
}

extern "C" void kernel_launch(void* const* d_in, const int* in_sizes, int n_in,
                              void* d_out, int out_size, void* d_ws, size_t ws_size,
                              hipStream_t stream) {
  const float* x    = (const float*)d_in[0];
  const float* W0   = (const float*)d_in[1];
  const float* W1   = (const float*)d_in[2];
  const float* bias = (const float*)d_in[3];
  float* out = (float*)d_out;
  char* w = (char*)d_ws;

  const size_t SZ_XN   = (size_t)NBN * CH * 4;   // 6,291,456
  const size_t SZ_XRAW = (size_t)NBN * CH * 4;   // 6,291,456
  const size_t SZ_CSQ  = (size_t)NBN * 4;        //   131,072
  const size_t SZ_NN   = (size_t)NBN * KNN * 2;  //   589,824
  const size_t SZ_DEG  = (size_t)NBN * 4;        //   131,072
  const size_t needF = SZ_XN + SZ_XRAW + SZ_CSQ + SZ_NN + 2 * SZ_DEG; // 13,565,952

  if (ws_size >= needF) {          // FAST path: 3 kernels
    float* xn   = (float*)w;
    float* xraw = (float*)(w + SZ_XN);
    float* csq  = (float*)(w + SZ_XN + SZ_XRAW);
    u16*   nn   = (u16*)  (w + SZ_XN + SZ_XRAW + SZ_CSQ);
    int*   deg  = (int*)  (w + SZ_XN + SZ_XRAW + SZ_CSQ + SZ_NN);
    k_prep  <<<NBN / 256, 256, 0, stream>>>(x, xraw, xn, csq, deg);
    k_knn   <<<NBN / RWB, 256, 0, stream>>>(xn, csq, nn, deg);
    k_out_f <<<NBN / ONB, 256, 0, stream>>>(xraw, nn, deg, W0, W1, bias, out);
  } else {                         // FALLBACK: proven round-4 path (852 KB)
    u16*   nn   = (u16*)w;
    int*   deg  = (int*)(w + SZ_NN);
    float* dinv = (float*)(w + SZ_NN + SZ_DEG);
    k_knn_nb <<<NBN / RPB, 256, 0, stream>>>(x, nn);
    k_zero   <<<NBN / 256, 256, 0, stream>>>(deg);
    k_hist   <<<NBN / 256, 256, 0, stream>>>(nn, deg);
    k_dinv   <<<NBN / 256, 256, 0, stream>>>(deg, dinv);
    k_out_nb <<<NBN / 256, 256, 0, stream>>>(x, nn, dinv, W0, W1, bias, out);
  }
}